// Round 1
// baseline (28.483 us; speedup 1.0000x reference)
//
#include <hip/hip_runtime.h>

// AttnCutLoss: loss = -(1/B) * sum_b [ (sum_s log(output[b,s])) / (sum_s exp(r_bs/TAU)) ]
// with r_bs = 2*tp_bs / (k + total_b)  (F1 metric, algebraically simplified; exact for
// tp=0 and total=0 edge cases of the reference's where() chain).
// B = S = 4096, TAU = 0.95, fp32 in/out.

#define BDIM 512
#define SROW 4096
#define NROWS 4096

__global__ __launch_bounds__(BDIM) void attncut_row_kernel(
    const float* __restrict__ output,   // [B,S,1] contiguous
    const float* __restrict__ labels,   // [B,S]
    float* __restrict__ row_out)        // [B] : L_b / norm_b
{
    const int b    = blockIdx.x;
    const int tid  = threadIdx.x;       // 0..511
    const int lane = tid & 63;
    const int wave = tid >> 6;          // 0..7

    const float* lab = labels + (size_t)b * SROW;
    const float* out = output + (size_t)b * SROW;

    // Each thread handles 8 consecutive elements: [tid*8, tid*8+8)
    const int base = tid * 8;
    float4 l0 = *reinterpret_cast<const float4*>(lab + base);
    float4 l1 = *reinterpret_cast<const float4*>(lab + base + 4);
    float v[8] = {l0.x, l0.y, l0.z, l0.w, l1.x, l1.y, l1.z, l1.w};

    // thread-local inclusive prefix (labels are exactly 0.0f/1.0f -> exact in fp32)
    float pre[8];
    float acc = 0.f;
    #pragma unroll
    for (int i = 0; i < 8; ++i) { acc += v[i]; pre[i] = acc; }
    const float cnt = acc;

    // wave-level inclusive scan of per-thread counts
    float sc = cnt;
    #pragma unroll
    for (int d = 1; d < 64; d <<= 1) {
        float n = __shfl_up(sc, d, 64);
        if (lane >= d) sc += n;
    }

    __shared__ float wtot[8];
    __shared__ float wpre[8];
    __shared__ float s_total;
    if (lane == 63) wtot[wave] = sc;
    __syncthreads();
    if (tid == 0) {
        float a = 0.f;
        #pragma unroll
        for (int w = 0; w < 8; ++w) { wpre[w] = a; a += wtot[w]; }
        s_total = a;
    }
    __syncthreads();
    const float total = s_total;
    const float excl  = wpre[wave] + (sc - cnt);  // elements strictly before this chunk

    // fused: q = exp(2*tp / (TAU*(k+total))), lsum = sum log(output)
    float4 o0 = *reinterpret_cast<const float4*>(out + base);
    float4 o1 = *reinterpret_cast<const float4*>(out + base + 4);
    float o[8] = {o0.x, o0.y, o0.z, o0.w, o1.x, o1.y, o1.z, o1.w};

    float qsum = 0.f, lsum = 0.f;
    const float two_over_tau = 2.0f / 0.95f;
    #pragma unroll
    for (int i = 0; i < 8; ++i) {
        float tp = excl + pre[i];
        float k  = (float)(base + i + 1);
        qsum += __expf(two_over_tau * tp / (k + total));
        lsum += __logf(o[i]);
    }

    // block reduction of (qsum, lsum)
    #pragma unroll
    for (int d = 32; d > 0; d >>= 1) {
        qsum += __shfl_down(qsum, d, 64);
        lsum += __shfl_down(lsum, d, 64);
    }
    __shared__ float sq[8], sl[8];
    if (lane == 0) { sq[wave] = qsum; sl[wave] = lsum; }
    __syncthreads();
    if (tid == 0) {
        float Q = 0.f, L = 0.f;
        #pragma unroll
        for (int w = 0; w < 8; ++w) { Q += sq[w]; L += sl[w]; }
        row_out[b] = L / Q;
    }
}

__global__ __launch_bounds__(1024) void attncut_final_kernel(
    const float* __restrict__ row_out, float* __restrict__ d_out)
{
    const int tid = threadIdx.x;
    float s = 0.f;
    for (int i = tid; i < NROWS; i += 1024) s += row_out[i];
    #pragma unroll
    for (int d = 32; d > 0; d >>= 1) s += __shfl_down(s, d, 64);
    __shared__ float sm[16];
    const int lane = tid & 63, wave = tid >> 6;
    if (lane == 0) sm[wave] = s;
    __syncthreads();
    if (tid == 0) {
        float t = 0.f;
        #pragma unroll
        for (int w = 0; w < 16; ++w) t += sm[w];
        d_out[0] = -t / (float)NROWS;
    }
}

extern "C" void kernel_launch(void* const* d_in, const int* in_sizes, int n_in,
                              void* d_out, int out_size, void* d_ws, size_t ws_size,
                              hipStream_t stream) {
    const float* output = (const float*)d_in[0];   // [B,S,1] fp32
    const float* labels = (const float*)d_in[1];   // [B,S]   fp32
    float* out  = (float*)d_out;
    float* rows = (float*)d_ws;                    // NROWS floats of scratch

    attncut_row_kernel<<<NROWS, BDIM, 0, stream>>>(output, labels, rows);
    attncut_final_kernel<<<1, 1024, 0, stream>>>(rows, out);
}

// Round 2
// 28.260 us; speedup vs baseline: 1.0079x; 1.0079x over previous
//
#include <hip/hip_runtime.h>

// AttnCutLoss: loss = -(1/B) * sum_b [ (sum_s log(output[b,s])) / (sum_s exp(r_bs/TAU)) ]
// r_bs = 2*tp_bs / (k + total_b)   (F1, algebraically simplified; exact for the
// reference's tp=0 / total=0 where() branches).  B = S = 4096, TAU = 0.95, fp32.

#define BDIM 256
#define VPT 16              // values per thread; BDIM*VPT == SROW
#define SROW 4096
#define NROWS 4096

__global__ __launch_bounds__(BDIM) void attncut_row_kernel(
    const float* __restrict__ output,   // [B,S,1]
    const float* __restrict__ labels,   // [B,S]
    float* __restrict__ row_out)        // [B] : L_b / norm_b
{
    const int b    = blockIdx.x;
    const int tid  = threadIdx.x;       // 0..255
    const int lane = tid & 63;
    const int wave = tid >> 6;          // 0..3
    const int base = tid * VPT;

    const float* lab = labels + (size_t)b * SROW + base;
    const float* out = output + (size_t)b * SROW + base;

    // Issue ALL loads up front so both arrays' latency overlaps the scan.
    float4 Lv[4], Ov[4];
    #pragma unroll
    for (int i = 0; i < 4; ++i) Lv[i] = reinterpret_cast<const float4*>(lab)[i];
    #pragma unroll
    for (int i = 0; i < 4; ++i) Ov[i] = reinterpret_cast<const float4*>(out)[i];

    float v[VPT], o[VPT];
    #pragma unroll
    for (int i = 0; i < 4; ++i) {
        v[4*i+0] = Lv[i].x; v[4*i+1] = Lv[i].y; v[4*i+2] = Lv[i].z; v[4*i+3] = Lv[i].w;
        o[4*i+0] = Ov[i].x; o[4*i+1] = Ov[i].y; o[4*i+2] = Ov[i].z; o[4*i+3] = Ov[i].w;
    }

    // Thread-local inclusive prefix of labels (exact: labels are 0.0/1.0).
    float pre[VPT];
    float acc = 0.f;
    #pragma unroll
    for (int i = 0; i < VPT; ++i) { acc += v[i]; pre[i] = acc; }
    const float cnt = acc;

    // Log-sum now: trans-pipe work that overlaps other waves' scan/barrier.
    float lsum = 0.f;
    #pragma unroll
    for (int i = 0; i < VPT; ++i) lsum += __logf(o[i]);

    // Wave-level inclusive scan of per-thread counts.
    float sc = cnt;
    #pragma unroll
    for (int d = 1; d < 64; d <<= 1) {
        float n = __shfl_up(sc, d, 64);
        if (lane >= d) sc += n;
    }

    __shared__ float wtot[4], wpre[4];
    __shared__ float s_total;
    if (lane == 63) wtot[wave] = sc;
    __syncthreads();
    if (tid == 0) {
        float a = 0.f;
        #pragma unroll
        for (int w = 0; w < 4; ++w) { wpre[w] = a; a += wtot[w]; }
        s_total = a;
    }
    __syncthreads();
    const float total = s_total;
    const float excl  = wpre[wave] + (sc - cnt);   // labels strictly before this chunk

    // qsum = sum exp(2*tp / (TAU*(k+total)))  with fast rcp instead of IEEE divide.
    const float c = 2.0f / 0.95f;
    float qsum = 0.f;
    #pragma unroll
    for (int i = 0; i < VPT; ++i) {
        float tp = excl + pre[i];
        float kf = (float)(base + i + 1) + total;
        qsum += __expf(c * tp * __builtin_amdgcn_rcpf(kf));
    }

    // Block reduction of (qsum, lsum).
    #pragma unroll
    for (int d = 32; d > 0; d >>= 1) {
        qsum += __shfl_down(qsum, d, 64);
        lsum += __shfl_down(lsum, d, 64);
    }
    __shared__ float sq[4], sl[4];
    if (lane == 0) { sq[wave] = qsum; sl[wave] = lsum; }
    __syncthreads();
    if (tid == 0) {
        float Q = 0.f, L = 0.f;
        #pragma unroll
        for (int w = 0; w < 4; ++w) { Q += sq[w]; L += sl[w]; }
        row_out[b] = L / Q;
    }
}

__global__ __launch_bounds__(1024) void attncut_final_kernel(
    const float* __restrict__ row_out, float* __restrict__ d_out)
{
    const int tid = threadIdx.x;
    float s = 0.f;
    for (int i = tid; i < NROWS; i += 1024) s += row_out[i];
    #pragma unroll
    for (int d = 32; d > 0; d >>= 1) s += __shfl_down(s, d, 64);
    __shared__ float sm[16];
    const int lane = tid & 63, wave = tid >> 6;
    if (lane == 0) sm[wave] = s;
    __syncthreads();
    if (tid == 0) {
        float t = 0.f;
        #pragma unroll
        for (int w = 0; w < 16; ++w) t += sm[w];
        d_out[0] = -t / (float)NROWS;
    }
}

extern "C" void kernel_launch(void* const* d_in, const int* in_sizes, int n_in,
                              void* d_out, int out_size, void* d_ws, size_t ws_size,
                              hipStream_t stream) {
    const float* output = (const float*)d_in[0];   // [B,S,1] fp32
    const float* labels = (const float*)d_in[1];   // [B,S]   fp32
    float* out  = (float*)d_out;
    float* rows = (float*)d_ws;                    // NROWS floats of scratch

    attncut_row_kernel<<<NROWS, BDIM, 0, stream>>>(output, labels, rows);
    attncut_final_kernel<<<1, 1024, 0, stream>>>(rows, out);
}